// Round 6
// baseline (269.793 us; speedup 1.0000x reference)
//
#include <hip/hip_runtime.h>

constexpr int Bn = 32;
constexpr int Cn = 128;
constexpr int Mn = 4000;
constexpr int Gn = 4;
constexpr int Dn = 32;   // C / G
constexpr float GN_EPS = 1e-5f;
constexpr float IN_EPS = 1e-3f;
constexpr float BN_EPS = 1e-5f;

typedef __attribute__((ext_vector_type(8))) short bf16x8;
typedef __attribute__((ext_vector_type(4))) float f32x4;
typedef __attribute__((ext_vector_type(16))) float f32x16;

__device__ __forceinline__ float bf2f(ushort u) {
    union { unsigned int u; float f; } v;
    v.u = ((unsigned int)u) << 16;
    return v.f;
}
__device__ __forceinline__ ushort f2bf(float f) {
    union { float f; unsigned int u; } v;
    v.f = f;
    unsigned int r = v.u + 0x7FFFu + ((v.u >> 16) & 1u);
    return (ushort)(r >> 16);
}

// ---------------------------------------------------------------------------
// prep_w3: three fp32 W[128][128] -> bf16, one launch (grid 192 x 256)
// ---------------------------------------------------------------------------
__global__ void prep_w3(const float* __restrict__ w0, const float* __restrict__ w1,
                        const float* __restrict__ w2, ushort* __restrict__ wb) {
    const int i = blockIdx.x * 256 + threadIdx.x;   // 49152 total
    const int which = i >> 14;
    const int off = i & 16383;
    const float v = (which == 0) ? w0[off] : (which == 1) ? w1[off] : w2[off];
    wb[i] = f2bf(v);
}

// ---------------------------------------------------------------------------
// prep_xt: x [b][c][m] fp32 -> xt [b][m][c] bf16 (32x32 LDS tile transpose)
// grid (Mn/32, Cn/32, Bn)
// ---------------------------------------------------------------------------
__launch_bounds__(256)
__global__ void prep_xt(const float* __restrict__ x, ushort* __restrict__ xt) {
    __shared__ float tl[32 * 33];
    const int mb = blockIdx.x * 32, cb = blockIdx.y * 32, b = blockIdx.z;
    const int tid = threadIdx.x;
    const int mi = tid & 31;
#pragma unroll
    for (int p = 0; p < 4; ++p) {
        const int ci = (tid >> 5) + 8 * p;
        tl[ci * 33 + mi] = x[((size_t)b * Cn + cb + ci) * Mn + mb + mi];
    }
    __syncthreads();
#pragma unroll
    for (int p = 0; p < 4; ++p) {
        const int mi2 = (tid >> 5) + 8 * p;
        const int ci2 = tid & 31;
        xt[((size_t)b * Mn + mb + mi2) * Cn + cb + ci2] = f2bf(tl[ci2 * 33 + mi2]);
    }
}

// ---------------------------------------------------------------------------
// MFMA GEMM, barrier-free: D[b][m][o] = sum_c T(src[b][m][c]) * W[o][c]
// W read directly from global (32 KB, L1/L2-resident, shared by all blocks).
// block: 256 thr = 4 waves; tile 64m x 128o; wave = 16m x 128o.
// grid: (ceil(Mn/64), Bn)
// ---------------------------------------------------------------------------
template <int MODE>
__launch_bounds__(256)
__global__ void mgemm_kernel(const ushort* __restrict__ Wb,
                             const ushort* __restrict__ src,
                             const ushort* __restrict__ xsrc,
                             ushort* __restrict__ dst_bf,
                             float* __restrict__ dst_f32,
                             const float* __restrict__ bias,
                             const float* __restrict__ sarr,
                             const float* __restrict__ tA,
                             const float* __restrict__ tB,
                             const float* __restrict__ Ayc,
                             const float* __restrict__ Byc,
                             ushort* __restrict__ ybuf,
                             float* __restrict__ sum1,
                             float* __restrict__ sum2)
{
    const int b = blockIdx.y;
    const int mb = blockIdx.x * 64;
    const int tid = threadIdx.x;
    const int wv = tid >> 6, l = tid & 63;
    const int li = l & 15, lg = l >> 4;

    f32x4 acc[8];
#pragma unroll
    for (int j = 0; j < 8; ++j)
#pragma unroll
        for (int r = 0; r < 4; ++r) acc[j][r] = 0.f;

    const int ma = mb + wv * 16 + li;      // a-frag row for this lane
    const bool mok = ma < Mn;
    const size_t qrow = ((size_t)b * Mn + (mok ? ma : 0)) * Cn;

#pragma unroll
    for (int kb = 0; kb < 4; ++kb) {
        const int cl = kb * 32 + 8 * lg;   // lane's c-base (8 consecutive c)

        bf16x8 af;
#pragma unroll
        for (int e = 0; e < 8; ++e) af[e] = 0;

        if (MODE == 0) {
            if (mok) af = *(const bf16x8*)(src + qrow + cl);
        } else if (MODE == 1) {
            const float4 a0 = *(const float4*)(tA + b * Cn + cl);
            const float4 a1 = *(const float4*)(tA + b * Cn + cl + 4);
            const float4 b0 = *(const float4*)(tB + b * Cn + cl);
            const float4 b1 = *(const float4*)(tB + b * Cn + cl + 4);
            const float4 s0 = *(const float4*)(sarr + b * Cn + cl);
            const float4 s1 = *(const float4*)(sarr + b * Cn + cl + 4);
            const float4 y0 = *(const float4*)(Ayc + b * Cn + cl);
            const float4 y1 = *(const float4*)(Ayc + b * Cn + cl + 4);
            const float4 z0 = *(const float4*)(Byc + b * Cn + cl);
            const float4 z1 = *(const float4*)(Byc + b * Cn + cl + 4);
            const float tAv[8] = {a0.x,a0.y,a0.z,a0.w,a1.x,a1.y,a1.z,a1.w};
            const float tBv[8] = {b0.x,b0.y,b0.z,b0.w,b1.x,b1.y,b1.z,b1.w};
            const float svv[8] = {s0.x,s0.y,s0.z,s0.w,s1.x,s1.y,s1.z,s1.w};
            const float ayv[8] = {y0.x,y0.y,y0.z,y0.w,y1.x,y1.y,y1.z,y1.w};
            const float byv[8] = {z0.x,z0.y,z0.z,z0.w,z1.x,z1.y,z1.z,z1.w};
            if (mok) {
                const bf16x8 f8 = *(const bf16x8*)(src + qrow + cl);
                const bf16x8 x8 = *(const bf16x8*)(xsrc + qrow + cl);
                bf16x8 y8;
#pragma unroll
                for (int e = 0; e < 8; ++e) {
                    const float vv = fmaf(svv[e], bf2f((ushort)f8[e]), bf2f((ushort)x8[e]));
                    af[e] = (short)f2bf(fmaxf(fmaf(tAv[e], vv, tBv[e]), 0.f));
                    y8[e] = (short)f2bf(fmaf(ayv[e], vv, byv[e]));
                }
                *(bf16x8*)(ybuf + qrow + cl) = y8;
            }
        } else {
            const float4 a0 = *(const float4*)(tA + b * Cn + cl);
            const float4 a1 = *(const float4*)(tA + b * Cn + cl + 4);
            const float4 b0 = *(const float4*)(tB + b * Cn + cl);
            const float4 b1 = *(const float4*)(tB + b * Cn + cl + 4);
            const float tAv[8] = {a0.x,a0.y,a0.z,a0.w,a1.x,a1.y,a1.z,a1.w};
            const float tBv[8] = {b0.x,b0.y,b0.z,b0.w,b1.x,b1.y,b1.z,b1.w};
            if (mok) {
                const bf16x8 f8 = *(const bf16x8*)(src + qrow + cl);
#pragma unroll
                for (int e = 0; e < 8; ++e)
                    af[e] = (short)f2bf(fmaxf(fmaf(tAv[e], bf2f((ushort)f8[e]), tBv[e]), 0.f));
            }
        }

#pragma unroll
        for (int j = 0; j < 8; ++j) {
            const bf16x8 bj = *(const bf16x8*)(Wb + (size_t)(j * 16 + li) * Cn + cl);
            acc[j] = __builtin_amdgcn_mfma_f32_16x16x32_bf16(af, bj, acc[j], 0, 0, 0);
        }
    }

    // ---------------- epilogues ----------------
    if constexpr (MODE == 0) {
#pragma unroll
        for (int j = 0; j < 8; ++j) {
            const int o = j * 16 + li;
#pragma unroll
            for (int r = 0; r < 4; ++r) {
                const int m = mb + wv * 16 + lg * 4 + r;
                if (m < Mn)
                    dst_bf[((size_t)b * Mn + m) * Cn + o] = f2bf(acc[j][r]);
            }
        }
    } else if constexpr (MODE == 1) {
#pragma unroll
        for (int j = 0; j < 8; ++j) {
            const int o = j * 16 + li;
            const float bv = bias[o];
            float s1 = 0.f, s2 = 0.f;
#pragma unroll
            for (int r = 0; r < 4; ++r) {
                const int m = mb + wv * 16 + lg * 4 + r;
                if (m < Mn) {
                    const float v = acc[j][r] + bv;
                    dst_bf[((size_t)b * Mn + m) * Cn + o] = f2bf(v);
                    s1 += v;
                    s2 = fmaf(v, v, s2);
                }
            }
            s1 += __shfl_xor(s1, 16); s1 += __shfl_xor(s1, 32);
            s2 += __shfl_xor(s2, 16); s2 += __shfl_xor(s2, 32);
            if (lg == 0) {
                atomicAdd(&sum1[b * Cn + o], s1);
                atomicAdd(&sum2[b * Cn + o], s2);
            }
        }
    } else {
        __shared__ union ETile {
            ushort y[64 * 136];
            float  tr[64 * 68];
        } eLDS;
#pragma unroll
        for (int p = 0; p < 4; ++p) {
            const int u = tid + 256 * p;           // 1024 chunks
            const int row = u >> 4, c8 = (u & 15) * 8;
            bf16x8 yv;
#pragma unroll
            for (int e = 0; e < 8; ++e) yv[e] = 0;
            if (mb + row < Mn)
                yv = *(const bf16x8*)(ybuf + ((size_t)b * Mn + mb + row) * Cn + c8);
            *(bf16x8*)&eLDS.y[row * 136 + c8] = yv;
        }
        __syncthreads();
#pragma unroll
        for (int j = 0; j < 8; ++j) {
            const int o = j * 16 + li;
            const float bv = bias[o];
#pragma unroll
            for (int r = 0; r < 4; ++r) {
                const int ml = wv * 16 + lg * 4 + r;
                acc[j][r] += bv + bf2f(eLDS.y[ml * 136 + o]);
            }
        }
#pragma unroll
        for (int h = 0; h < 2; ++h) {
            __syncthreads();
#pragma unroll
            for (int jj = 0; jj < 4; ++jj) {
                const int j = h * 4 + jj;
#pragma unroll
                for (int r = 0; r < 4; ++r) {
                    const int ml = wv * 16 + lg * 4 + r;
                    eLDS.tr[(jj * 16 + li) * 68 + ml] = acc[j][r];
                }
            }
            __syncthreads();
#pragma unroll
            for (int p = 0; p < 4; ++p) {
                const int ol = tid >> 2;                 // 0..63
                const int q = (tid & 3) + 4 * p;         // 0..15
                const int m = mb + 4 * q;
                if (m < Mn) {
                    const f32x4 v = *(const f32x4*)&eLDS.tr[ol * 68 + 4 * q];
                    *(f32x4*)(dst_f32 + ((size_t)b * Cn + h * 64 + ol) * Mn + m) = v;
                }
            }
        }
    }
}

// ---------------------------------------------------------------------------
// Covariance via MFMA (A==B fragment trick) + channel sums.
// grid: (CVSPLIT, Gn, Bn), 256 threads = 4 waves.
// ---------------------------------------------------------------------------
constexpr int CVSPLIT = 8;
constexpr int CVSEG = Mn / CVSPLIT;   // 500
constexpr int CVMT = 128;             // m per tile (64 u32 pairs)

__launch_bounds__(256)
__global__ void cov_kernel(const ushort* __restrict__ featt, const ushort* __restrict__ xt,
                           float* __restrict__ cov,
                           float* __restrict__ sf, float* __restrict__ sf2,
                           float* __restrict__ sfx, float* __restrict__ sx,
                           float* __restrict__ sx2)
{
    __shared__ unsigned int tl[32 * 66];   // [c 0..31][mp 0..63], stride 66
    __shared__ float red[4][1040];
    const int sp = blockIdx.x, g = blockIdx.y, b = blockIdx.z;
    const int tid = threadIdx.x;
    const int wv = tid >> 6, l = tid & 63;
    const int c8 = wv * 8;                  // wave-uniform channel octet
    const int m0 = sp * CVSEG;

    f32x16 acc;
#pragma unroll
    for (int i = 0; i < 16; ++i) acc[i] = 0.f;
    float cf[8] = {}, cf2[8] = {}, cfx[8] = {}, cx[8] = {}, cx2[8] = {};

    const int ldaddr = (l & 31) * 66 + ((l >> 5) << 2);

    for (int t0 = 0; t0 < CVSEG; t0 += CVMT) {
        const int lim = (CVSEG - t0 < CVMT) ? (CVSEG - t0) : CVMT;
        const int mloc = 2 * l;
        unsigned int pk[8];
        if (mloc + 1 < lim) {
            const size_t base = ((size_t)b * Mn + m0 + t0 + mloc) * Cn + g * Dn + c8;
            const bf16x8 f0 = *(const bf16x8*)(featt + base);
            const bf16x8 f1 = *(const bf16x8*)(featt + base + Cn);
            const bf16x8 x0 = *(const bf16x8*)(xt + base);
            const bf16x8 x1 = *(const bf16x8*)(xt + base + Cn);
#pragma unroll
            for (int e = 0; e < 8; ++e) {
                const float fa = bf2f((ushort)f0[e]), fb = bf2f((ushort)f1[e]);
                const float xa = bf2f((ushort)x0[e]), xb = bf2f((ushort)x1[e]);
                cf[e]  += fa + fb;
                cf2[e]  = fmaf(fa, fa, fmaf(fb, fb, cf2[e]));
                cfx[e]  = fmaf(fa, xa, fmaf(fb, xb, cfx[e]));
                cx[e]  += xa + xb;
                cx2[e]  = fmaf(xa, xa, fmaf(xb, xb, cx2[e]));
                pk[e] = (unsigned int)(ushort)f0[e] | ((unsigned int)(ushort)f1[e] << 16);
            }
        } else {
#pragma unroll
            for (int e = 0; e < 8; ++e) pk[e] = 0;
        }
        __syncthreads();
#pragma unroll
        for (int e = 0; e < 8; ++e)
            tl[(c8 + e) * 66 + l] = pk[e];
        __syncthreads();
#pragma unroll
        for (int s = 0; s < 2; ++s) {
            const int mpb = wv * 16 + s * 8;
            const uint4 rv = *(const uint4*)&tl[ldaddr + mpb];
            union { uint4 u; bf16x8 h; } cvt;
            cvt.u = rv;
            acc = __builtin_amdgcn_mfma_f32_32x32x16_bf16(cvt.h, cvt.h, acc, 0, 0, 0);
        }
    }

#pragma unroll
    for (int i = 0; i < 16; ++i) red[wv][l * 16 + i] = acc[i];
    __syncthreads();
    float* cvb = cov + (size_t)(b * Gn + g) * (Dn * Dn);
    for (int e2 = tid; e2 < 1024; e2 += 256) {
        const int ll = e2 >> 4, reg = e2 & 15;
        const float v = red[0][e2] + red[1][e2] + red[2][e2] + red[3][e2];
        const int i = (reg & 3) + 8 * (reg >> 2) + 4 * (ll >> 5);
        const int j = ll & 31;
        atomicAdd(&cvb[i * Dn + j], v);
    }

#pragma unroll
    for (int e = 0; e < 8; ++e) {
#pragma unroll
        for (int d = 1; d < 64; d <<= 1) {
            cf[e]  += __shfl_xor(cf[e], d);
            cf2[e] += __shfl_xor(cf2[e], d);
            cfx[e] += __shfl_xor(cfx[e], d);
            cx[e]  += __shfl_xor(cx[e], d);
            cx2[e] += __shfl_xor(cx2[e], d);
        }
    }
    if (l == 0) {
        const int ch = b * Cn + g * Dn + c8;
#pragma unroll
        for (int e = 0; e < 8; ++e) {
            atomicAdd(&sf[ch + e],  cf[e]);
            atomicAdd(&sf2[ch + e], cf2[e]);
            atomicAdd(&sfx[ch + e], cfx[e]);
            atomicAdd(&sx[ch + e],  cx[e]);
            atomicAdd(&sx2[ch + e], cx2[e]);
        }
    }
}

// ---------------------------------------------------------------------------
// Newton-Schulz sqrtm per (b,g) 32x32 + row-mean -> s[b,c]
// ---------------------------------------------------------------------------
__device__ __forceinline__ void mm32(float (*A)[33], float (*Bm)[33],
                                     float (*O)[33], int ei, int ej0)
{
    float a0 = 0.f, a1 = 0.f, a2 = 0.f, a3 = 0.f;
#pragma unroll
    for (int k = 0; k < 32; ++k) {
        const float a = A[ei][k];
        a0 = fmaf(a, Bm[k][ej0 + 0], a0);
        a1 = fmaf(a, Bm[k][ej0 + 1], a1);
        a2 = fmaf(a, Bm[k][ej0 + 2], a2);
        a3 = fmaf(a, Bm[k][ej0 + 3], a3);
    }
    O[ei][ej0 + 0] = a0;
    O[ei][ej0 + 1] = a1;
    O[ei][ej0 + 2] = a2;
    O[ei][ej0 + 3] = a3;
    __syncthreads();
}

__launch_bounds__(256)
__global__ void sqrtm_kernel(const float* __restrict__ cov,
                             const float* __restrict__ sf,
                             float* __restrict__ sout)
{
    __shared__ float b0[32][33], b1[32][33], b2[32][33], b3[32][33];
    __shared__ float sh_tr, sh_scale;
    const int bg = blockIdx.x;
    const int b = bg >> 2, g = bg & 3;
    const int tid = threadIdx.x;
    const int ei = (tid * 4) >> 5, ej0 = (tid * 4) & 31;
    const float* cp = cov + (size_t)bg * (Dn * Dn);
    const float* fs = sf + b * Cn + g * Dn;
    const float invM = 1.f / Mn;
    const float mi = fs[ei] * invM;
#pragma unroll
    for (int q = 0; q < 4; ++q)
        b0[ei][ej0 + q] = cp[ei * Dn + ej0 + q] * invM - mi * (fs[ej0 + q] * invM);
    __syncthreads();
    if (tid < 32) {
        float d = b0[tid][tid];
#pragma unroll
        for (int dd = 1; dd < 32; dd <<= 1) d += __shfl_xor(d, dd);
        if (tid == 0) { sh_tr = d; sh_scale = 0.5f * sqrtf(d); }
    }
    __syncthreads();
    const float invtr = 1.f / sh_tr;
#pragma unroll
    for (int q = 0; q < 4; ++q) {
        const float an = b0[ei][ej0 + q] * invtr;
        b0[ei][ej0 + q] = an;
        b1[ei][ej0 + q] = ((ei == ej0 + q) ? 1.5f : 0.f) - 0.5f * an;
    }
    __syncthreads();
    mm32(b0, b1, b2, ei, ej0);  // Y = An @ ZY
    float (*pY)[33] = b2;
    float (*pZ)[33] = b1;
    float (*pF1)[33] = b0;
    float (*pF2)[33] = b3;
#pragma unroll 1
    for (int it = 0; it < 3; ++it) {
        mm32(pZ, pY, pF1, ei, ej0);
#pragma unroll
        for (int q = 0; q < 4; ++q)
            pF1[ei][ej0 + q] = ((ei == ej0 + q) ? 1.5f : 0.f) - 0.5f * pF1[ei][ej0 + q];
        __syncthreads();
        mm32(pY, pF1, pF2, ei, ej0);
        mm32(pF1, pZ, pY, ei, ej0);
        float (*oldZ)[33] = pZ;
        pZ = pY;
        pY = pF2;
        pF2 = oldZ;
    }
    mm32(pZ, pY, pF1, ei, ej0);
#pragma unroll
    for (int q = 0; q < 4; ++q)
        pF1[ei][ej0 + q] = ((ei == ej0 + q) ? 3.f : 0.f) - pF1[ei][ej0 + q];
    __syncthreads();
    mm32(pY, pF1, pF2, ei, ej0);
    if (tid < 32) {
        float t = 0.f;
#pragma unroll
        for (int i = 0; i < 32; ++i) t += pF2[i][tid];
        sout[b * Cn + g * Dn + tid] = t * sh_scale * (1.f / Dn);
    }
}

// ---------------------------------------------------------------------------
// coef1 / coef2 (analytic affine propagation)
// ---------------------------------------------------------------------------
__launch_bounds__(1024)
__global__ void coef1_kernel(const float* __restrict__ sf, const float* __restrict__ sf2,
                             const float* __restrict__ sfx, const float* __restrict__ sx,
                             const float* __restrict__ sx2, const float* __restrict__ s,
                             const float* __restrict__ gng, const float* __restrict__ gnb,
                             const float* __restrict__ bn1g, const float* __restrict__ bn1b,
                             float* __restrict__ Ay, float* __restrict__ By,
                             float* __restrict__ Ah, float* __restrict__ Bh)
{
    __shared__ float smv[Bn * Cn];
    __shared__ float sm2[Bn * Cn];
    __shared__ float smu[Bn * Gn], srs[Bn * Gn];
    __shared__ float sV[Cn];
    const int tid = threadIdx.x;
    const float invM = 1.f / Mn;
    for (int p = tid; p < Bn * Cn; p += 1024) {
        const float sv = s[p];
        smv[p] = fmaf(sv, sf[p], sx[p]) * invM;
        sm2[p] = (sv * sv * sf2[p] + 2.f * sv * sfx[p] + sx2[p]) * invM;
    }
    __syncthreads();
    if (tid < Bn * Gn) {
        const int base = tid * Dn;
        float mu = 0.f, e2 = 0.f;
        for (int c = 0; c < Dn; ++c) { mu += smv[base + c]; e2 += sm2[base + c]; }
        mu *= (1.f / Dn); e2 *= (1.f / Dn);
        smu[tid] = mu;
        srs[tid] = rsqrtf(e2 - mu * mu + GN_EPS);
    }
    __syncthreads();
    for (int p = tid; p < Bn * Cn; p += 1024) {
        const int c = p & (Cn - 1);
        const int bg = p >> 5;
        const float ay = srs[bg] * gng[c];
        const float mv = smv[p];
        sm2[p] = ay * ay * (sm2[p] - mv * mv);
    }
    __syncthreads();
    if (tid < Cn) {
        float V = 0.f;
        for (int b = 0; b < Bn; ++b) {
            const float vy = sm2[b * Cn + tid];
            V += vy / (vy + IN_EPS);
        }
        sV[tid] = V * (1.f / Bn);
    }
    __syncthreads();
    for (int p = tid; p < Bn * Cn; p += 1024) {
        const int c = p & (Cn - 1);
        const int bg = p >> 5;
        const float ay = srs[bg] * gng[c];
        const float mv = smv[p];
        const float by = gnb[c] - smu[bg] * ay;
        const float rsin = rsqrtf(sm2[p] + IN_EPS);
        const float ah = ay * rsin * rsqrtf(sV[c] + BN_EPS) * bn1g[c];
        const float bh = bn1b[c] - ah * mv;
        Ay[p] = ay; By[p] = by; Ah[p] = ah; Bh[p] = bh;
    }
}

__launch_bounds__(1024)
__global__ void coef2_kernel(const float* __restrict__ sum1, const float* __restrict__ sum2,
                             const float* __restrict__ bn2g, const float* __restrict__ bn2b,
                             float* __restrict__ A2, float* __restrict__ B2)
{
    __shared__ float svar[Bn * Cn];
    __shared__ float sV[Cn];
    const int tid = threadIdx.x;
    const float invM = 1.f / Mn;
    for (int p = tid; p < Bn * Cn; p += 1024) {
        const float mu = sum1[p] * invM;
        svar[p] = sum2[p] * invM - mu * mu;
    }
    __syncthreads();
    if (tid < Cn) {
        float V = 0.f;
        for (int b = 0; b < Bn; ++b) {
            const float v = svar[b * Cn + tid];
            V += v / (v + IN_EPS);
        }
        sV[tid] = V * (1.f / Bn);
    }
    __syncthreads();
    for (int p = tid; p < Bn * Cn; p += 1024) {
        const int c = p & (Cn - 1);
        const float mu = sum1[p] * invM;
        const float a2 = rsqrtf(svar[p] + IN_EPS) * rsqrtf(sV[c] + BN_EPS) * bn2g[c];
        A2[p] = a2;
        B2[p] = bn2b[c] - a2 * mu;
    }
}

// ---------------------------------------------------------------------------
extern "C" void kernel_launch(void* const* d_in, const int* in_sizes, int n_in,
                              void* d_out, int out_size, void* d_ws, size_t ws_size,
                              hipStream_t stream)
{
    const float* x      = (const float*)d_in[0];
    const float* w_lin  = (const float*)d_in[1];
    const float* gn_g   = (const float*)d_in[2];
    const float* gn_b   = (const float*)d_in[3];
    const float* bn1g   = (const float*)d_in[4];
    const float* bn1b   = (const float*)d_in[5];
    const float* conv1w = (const float*)d_in[6];
    const float* conv1b = (const float*)d_in[7];
    const float* bn2g   = (const float*)d_in[8];
    const float* bn2b   = (const float*)d_in[9];
    const float* conv2w = (const float*)d_in[10];
    const float* conv2b = (const float*)d_in[11];
    float* out = (float*)d_out;

    const size_t TS = (size_t)Bn * Mn * Cn;
    ushort* xt    = (ushort*)d_ws;
    ushort* featt = xt + TS;
    ushort* h2t   = featt + TS;
    ushort* ybuf  = h2t + TS;
    ushort* wb1   = ybuf + TS;
    ushort* wb2   = wb1 + Cn * Cn;
    ushort* wb3   = wb2 + Cn * Cn;
    float*  fbase = (float*)(wb3 + Cn * Cn);
    float* sarr = fbase;
    float* Ay   = sarr + Bn * Cn;
    float* By   = Ay + Bn * Cn;
    float* Ah   = By + Bn * Cn;
    float* Bh   = Ah + Bn * Cn;
    float* A2   = Bh + Bn * Cn;
    float* B2   = A2 + Bn * Cn;
    float* zbase = B2 + Bn * Cn;
    float* cov  = zbase;
    float* sf   = cov + Bn * Gn * Dn * Dn;
    float* sf2  = sf + Bn * Cn;
    float* sfx  = sf2 + Bn * Cn;
    float* sx   = sfx + Bn * Cn;
    float* sx2  = sx + Bn * Cn;
    float* sum1 = sx2 + Bn * Cn;
    float* sum2 = sum1 + Bn * Cn;
    const size_t zfloats = (size_t)Bn * Gn * Dn * Dn + 7 * Bn * Cn;

    hipMemsetAsync(zbase, 0, zfloats * sizeof(float), stream);

    prep_w3<<<dim3(192), 256, 0, stream>>>(w_lin, conv1w, conv2w, wb1);
    prep_xt<<<dim3(Mn / 32, Cn / 32, Bn), 256, 0, stream>>>(x, xt);

    const dim3 ggrid((Mn + 63) / 64, Bn);

    // 1) featt = xt @ W1^T   ([b][m][o] bf16)
    mgemm_kernel<0><<<ggrid, 256, 0, stream>>>(
        wb1, xt, nullptr, featt, nullptr, nullptr, nullptr, nullptr, nullptr,
        nullptr, nullptr, nullptr, nullptr, nullptr);

    // 2) covariance (MFMA) + channel sums
    cov_kernel<<<dim3(CVSPLIT, Gn, Bn), 256, 0, stream>>>(featt, xt, cov, sf, sf2, sfx, sx, sx2);

    // 3) Newton-Schulz sqrtm -> s
    sqrtm_kernel<<<Bn * Gn, 256, 0, stream>>>(cov, sf, sarr);

    // 4) affine coefficients (GN + first IN/BN/ReLU)
    coef1_kernel<<<1, 1024, 0, stream>>>(sf, sf2, sfx, sx, sx2, sarr,
                                         gn_g, gn_b, bn1g, bn1b, Ay, By, Ah, Bh);

    // 5) h2t = relu(Ah*(s*featt+xt)+Bh) @ W2^T + b1, writes ybuf, stats
    mgemm_kernel<1><<<ggrid, 256, 0, stream>>>(
        wb2, featt, xt, h2t, nullptr, conv1b, sarr, Ah, Bh,
        Ay, By, ybuf, sum1, sum2);

    // 6) second-stage affine coefficients
    coef2_kernel<<<1, 1024, 0, stream>>>(sum1, sum2, bn2g, bn2b, A2, B2);

    // 7) out = relu(A2*h2t+B2) @ W3^T + b2 + y   ([b][o][m] fp32)
    mgemm_kernel<2><<<ggrid, 256, 0, stream>>>(
        wb3, h2t, nullptr, nullptr, out, conv2b, nullptr, A2, B2,
        nullptr, nullptr, ybuf, nullptr, nullptr);
}

// Round 7
// 173.008 us; speedup vs baseline: 1.5594x; 1.5594x over previous
//
#include <hip/hip_runtime.h>

constexpr int Bn = 32;
constexpr int Cn = 128;
constexpr int Mn = 4000;
constexpr int Gn = 4;
constexpr int Dn = 32;   // C / G
constexpr float GN_EPS = 1e-5f;
constexpr float IN_EPS = 1e-3f;
constexpr float BN_EPS = 1e-5f;

typedef __attribute__((ext_vector_type(8))) short bf16x8;
typedef __attribute__((ext_vector_type(4))) float f32x4;
typedef __attribute__((ext_vector_type(16))) float f32x16;

__device__ __forceinline__ float bf2f(ushort u) {
    union { unsigned int u; float f; } v;
    v.u = ((unsigned int)u) << 16;
    return v.f;
}
__device__ __forceinline__ ushort f2bf(float f) {
    union { float f; unsigned int u; } v;
    v.f = f;
    unsigned int r = v.u + 0x7FFFu + ((v.u >> 16) & 1u);
    return (ushort)(r >> 16);
}

// ---------------------------------------------------------------------------
// prep_w3: three fp32 W[128][128] -> bf16, one launch
// ---------------------------------------------------------------------------
__global__ void prep_w3(const float* __restrict__ w0, const float* __restrict__ w1,
                        const float* __restrict__ w2, ushort* __restrict__ wb) {
    const int i = blockIdx.x * 256 + threadIdx.x;   // 49152 total
    const int which = i >> 14;
    const int off = i & 16383;
    const float v = (which == 0) ? w0[off] : (which == 1) ? w1[off] : w2[off];
    wb[i] = f2bf(v);
}

// ---------------------------------------------------------------------------
// prep_xt: x [b][c][m] fp32 -> xt [b][m][c] bf16
// ---------------------------------------------------------------------------
__launch_bounds__(256)
__global__ void prep_xt(const float* __restrict__ x, ushort* __restrict__ xt) {
    __shared__ float tl[32 * 33];
    const int mb = blockIdx.x * 32, cb = blockIdx.y * 32, b = blockIdx.z;
    const int tid = threadIdx.x;
    const int mi = tid & 31;
#pragma unroll
    for (int p = 0; p < 4; ++p) {
        const int ci = (tid >> 5) + 8 * p;
        tl[ci * 33 + mi] = x[((size_t)b * Cn + cb + ci) * Mn + mb + mi];
    }
    __syncthreads();
#pragma unroll
    for (int p = 0; p < 4; ++p) {
        const int mi2 = (tid >> 5) + 8 * p;
        const int ci2 = tid & 31;
        xt[((size_t)b * Mn + mb + mi2) * Cn + cb + ci2] = f2bf(tl[ci2 * 33 + mi2]);
    }
}

// ---------------------------------------------------------------------------
// MFMA GEMM: D[b][m][o] = sum_c T(src[b][m][c]) * W[o][c]
// block 256 thr = 4 waves, tile 128m x 128o, W in LDS (once), coefs in LDS,
// raw a-frags register-hoisted per half-tile (one vmcnt wait per 8 loads).
// grid ((Mn+127)/128, Bn)
// ---------------------------------------------------------------------------
constexpr int WPAD = 136;

template <int MODE>
__launch_bounds__(256, 3)
__global__ void mgemm_kernel(const ushort* __restrict__ Wb,
                             const ushort* __restrict__ src,
                             const ushort* __restrict__ xsrc,
                             ushort* __restrict__ dst_bf,
                             float* __restrict__ dst_f32,
                             const float* __restrict__ bias,
                             const float* __restrict__ sarr,
                             const float* __restrict__ tA,
                             const float* __restrict__ tB,
                             const float* __restrict__ Ayc,
                             const float* __restrict__ Byc,
                             ushort* __restrict__ ybuf,
                             float* __restrict__ sum1,
                             float* __restrict__ sum2)
{
    __shared__ ushort Wl[128 * WPAD];     // 34816 B; reused by epilogues
    __shared__ float coefLDS[640];        // tA,tB,s,Ay,By  ([arr*128 + c])
    const int b = blockIdx.y;
    const int mb = blockIdx.x * 128;
    const int tid = threadIdx.x;
    const int wv = tid >> 6, l = tid & 63;
    const int li = l & 15, lg = l >> 4;

    // stage W -> LDS
#pragma unroll
    for (int p = 0; p < 8; ++p) {
        const int u = tid + 256 * p;
        const int o = u >> 4, c8 = (u & 15) * 8;
        *(bf16x8*)&Wl[o * WPAD + c8] = *(const bf16x8*)(Wb + o * 128 + c8);
    }
    // stage coefs -> LDS
    if (MODE >= 1) {
        const int ncoef = (MODE == 1) ? 640 : 256;
        for (int idx = tid; idx < ncoef; idx += 256) {
            const int arr = idx >> 7, c = idx & 127;
            float v;
            switch (arr) {
                case 0: v = tA[b * Cn + c]; break;
                case 1: v = tB[b * Cn + c]; break;
                case 2: v = sarr[b * Cn + c]; break;
                case 3: v = Ayc[b * Cn + c]; break;
                default: v = Byc[b * Cn + c]; break;
            }
            coefLDS[idx] = v;
        }
    }
    __syncthreads();

    f32x4 acc[2][8];
#pragma unroll
    for (int t = 0; t < 2; ++t)
#pragma unroll
        for (int j = 0; j < 8; ++j)
#pragma unroll
            for (int r = 0; r < 4; ++r) acc[t][j][r] = 0.f;

#pragma unroll
    for (int t = 0; t < 2; ++t) {
        const int ma = mb + wv * 32 + t * 16 + li;
        const bool mok = ma < Mn;
        const size_t qrow = ((size_t)b * Mn + (mok ? ma : 0)) * Cn;

        // phase 1: issue ALL raw loads for this half-tile
        bf16x8 fr[4], xr[4];
#pragma unroll
        for (int kb = 0; kb < 4; ++kb) {
            const int cl = kb * 32 + 8 * lg;
            if (mok) {
                fr[kb] = *(const bf16x8*)(src + qrow + cl);
                if (MODE == 1) xr[kb] = *(const bf16x8*)(xsrc + qrow + cl);
            } else {
#pragma unroll
                for (int e = 0; e < 8; ++e) { fr[kb][e] = 0; if (MODE == 1) xr[kb][e] = 0; }
            }
        }

        // phase 2: transform + MFMA
#pragma unroll
        for (int kb = 0; kb < 4; ++kb) {
            const int cl = kb * 32 + 8 * lg;
            bf16x8 af;
            if (MODE == 0) {
                af = fr[kb];
            } else if (MODE == 1) {
                const float4 a0 = *(const float4*)&coefLDS[0 + cl];
                const float4 a1 = *(const float4*)&coefLDS[0 + cl + 4];
                const float4 b0 = *(const float4*)&coefLDS[128 + cl];
                const float4 b1 = *(const float4*)&coefLDS[128 + cl + 4];
                const float4 s0 = *(const float4*)&coefLDS[256 + cl];
                const float4 s1 = *(const float4*)&coefLDS[256 + cl + 4];
                const float4 y0 = *(const float4*)&coefLDS[384 + cl];
                const float4 y1 = *(const float4*)&coefLDS[384 + cl + 4];
                const float4 z0 = *(const float4*)&coefLDS[512 + cl];
                const float4 z1 = *(const float4*)&coefLDS[512 + cl + 4];
                const float tAv[8] = {a0.x,a0.y,a0.z,a0.w,a1.x,a1.y,a1.z,a1.w};
                const float tBv[8] = {b0.x,b0.y,b0.z,b0.w,b1.x,b1.y,b1.z,b1.w};
                const float svv[8] = {s0.x,s0.y,s0.z,s0.w,s1.x,s1.y,s1.z,s1.w};
                const float ayv[8] = {y0.x,y0.y,y0.z,y0.w,y1.x,y1.y,y1.z,y1.w};
                const float byv[8] = {z0.x,z0.y,z0.z,z0.w,z1.x,z1.y,z1.z,z1.w};
                bf16x8 y8;
#pragma unroll
                for (int e = 0; e < 8; ++e) {
                    const float vv = fmaf(svv[e], bf2f((ushort)fr[kb][e]), bf2f((ushort)xr[kb][e]));
                    af[e] = (short)f2bf(fmaxf(fmaf(tAv[e], vv, tBv[e]), 0.f));
                    y8[e] = (short)f2bf(fmaf(ayv[e], vv, byv[e]));
                }
                if (mok) *(bf16x8*)(ybuf + qrow + cl) = y8;
            } else {
                const float4 a0 = *(const float4*)&coefLDS[0 + cl];
                const float4 a1 = *(const float4*)&coefLDS[0 + cl + 4];
                const float4 b0 = *(const float4*)&coefLDS[128 + cl];
                const float4 b1 = *(const float4*)&coefLDS[128 + cl + 4];
                const float tAv[8] = {a0.x,a0.y,a0.z,a0.w,a1.x,a1.y,a1.z,a1.w};
                const float tBv[8] = {b0.x,b0.y,b0.z,b0.w,b1.x,b1.y,b1.z,b1.w};
#pragma unroll
                for (int e = 0; e < 8; ++e)
                    af[e] = (short)f2bf(fmaxf(fmaf(tAv[e], bf2f((ushort)fr[kb][e]), tBv[e]), 0.f));
            }
#pragma unroll
            for (int j = 0; j < 8; ++j) {
                const bf16x8 bj = *(const bf16x8*)&Wl[(j * 16 + li) * WPAD + cl];
                acc[t][j] = __builtin_amdgcn_mfma_f32_16x16x32_bf16(af, bj, acc[t][j], 0, 0, 0);
            }
        }
    }

    // ---------------- epilogues ----------------
    if constexpr (MODE <= 1) {
        // stage (+bias) as bf16 into Wl[m][o], then coalesced bf16x8 stores
        __syncthreads();
#pragma unroll
        for (int t = 0; t < 2; ++t)
#pragma unroll
            for (int j = 0; j < 8; ++j) {
                const int o = j * 16 + li;
                const float bv = (MODE == 1) ? bias[o] : 0.f;
#pragma unroll
                for (int r = 0; r < 4; ++r) {
                    const int ml = wv * 32 + t * 16 + lg * 4 + r;
                    Wl[ml * WPAD + o] = f2bf(acc[t][j][r] + bv);
                }
            }
        __syncthreads();
        const int c8 = (tid & 15) * 8;
        float s1a[8] = {}, s2a[8] = {};
#pragma unroll
        for (int p = 0; p < 8; ++p) {
            const int row = (tid >> 4) + 16 * p;
            const int m = mb + row;
            const bf16x8 v8 = *(const bf16x8*)&Wl[row * WPAD + c8];
            if (m < Mn) {
                *(bf16x8*)(dst_bf + ((size_t)b * Mn + m) * Cn + c8) = v8;
                if (MODE == 1) {
#pragma unroll
                    for (int e = 0; e < 8; ++e) {
                        const float f = bf2f((ushort)v8[e]);
                        s1a[e] += f;
                        s2a[e] = fmaf(f, f, s2a[e]);
                    }
                }
            }
        }
        if (MODE == 1) {
#pragma unroll
            for (int e = 0; e < 8; ++e) {
                s1a[e] += __shfl_xor(s1a[e], 16); s1a[e] += __shfl_xor(s1a[e], 32);
                s2a[e] += __shfl_xor(s2a[e], 16); s2a[e] += __shfl_xor(s2a[e], 32);
            }
            __syncthreads();
            float* red = (float*)&Wl[0];   // [wv][oc 0..15][16]
            if (l < 16) {
#pragma unroll
                for (int e = 0; e < 8; ++e) {
                    red[(wv * 16 + l) * 16 + e] = s1a[e];
                    red[(wv * 16 + l) * 16 + 8 + e] = s2a[e];
                }
            }
            __syncthreads();
            if (tid < 128) {
                const int oc = tid >> 3, e = tid & 7;
                const int o = oc * 8 + e;
                const float t1 = red[(0 + oc) * 16 + e] + red[(16 + oc) * 16 + e] +
                                 red[(32 + oc) * 16 + e] + red[(48 + oc) * 16 + e];
                const float t2 = red[(0 + oc) * 16 + 8 + e] + red[(16 + oc) * 16 + 8 + e] +
                                 red[(32 + oc) * 16 + 8 + e] + red[(48 + oc) * 16 + 8 + e];
                atomicAdd(&sum1[b * Cn + o], t1);
                atomicAdd(&sum2[b * Cn + o], t2);
            }
        }
    } else {
        // MODE 2: stage y tile into Wl (coalesced), fold bias+y, transpose, store
        float* TR = (float*)&Wl[0];   // 64*132*4 = 33792 B <= 34816
        __syncthreads();
#pragma unroll
        for (int p = 0; p < 8; ++p) {
            const int u = tid + 256 * p;
            const int row = u >> 4, c8 = (u & 15) * 8;
            bf16x8 yv;
#pragma unroll
            for (int e = 0; e < 8; ++e) yv[e] = 0;
            if (mb + row < Mn)
                yv = *(const bf16x8*)(ybuf + ((size_t)b * Mn + mb + row) * Cn + c8);
            *(bf16x8*)&Wl[row * WPAD + c8] = yv;
        }
        __syncthreads();
#pragma unroll
        for (int j = 0; j < 8; ++j) {
            const int o = j * 16 + li;
            const float bv = bias[o];
#pragma unroll
            for (int t = 0; t < 2; ++t)
#pragma unroll
                for (int r = 0; r < 4; ++r) {
                    const int ml = wv * 32 + t * 16 + lg * 4 + r;
                    acc[t][j][r] += bv + bf2f(Wl[ml * WPAD + o]);
                }
        }
#pragma unroll
        for (int h = 0; h < 2; ++h) {
            __syncthreads();
#pragma unroll
            for (int jj = 0; jj < 4; ++jj) {
                const int j = h * 4 + jj;
#pragma unroll
                for (int t = 0; t < 2; ++t)
#pragma unroll
                    for (int r = 0; r < 4; ++r) {
                        const int ml = wv * 32 + t * 16 + lg * 4 + r;
                        TR[(jj * 16 + li) * 132 + ml] = acc[t][j][r];
                    }
            }
            __syncthreads();
#pragma unroll
            for (int p = 0; p < 8; ++p) {
                const int ol = tid >> 2;                 // 0..63
                const int q = (tid & 3) + 4 * p;         // 0..31
                const int m = mb + 4 * q;
                if (m < Mn) {
                    const f32x4 v = *(const f32x4*)&TR[ol * 132 + 4 * q];
                    *(f32x4*)(dst_f32 + ((size_t)b * Cn + h * 64 + ol) * Mn + m) = v;
                }
            }
        }
    }
}

// ---------------------------------------------------------------------------
// Covariance via MFMA (A==B fragment trick) + channel sums.
// grid: (CVSPLIT, Gn, Bn), 256 threads = 4 waves.
// ---------------------------------------------------------------------------
constexpr int CVSPLIT = 8;
constexpr int CVSEG = Mn / CVSPLIT;   // 500
constexpr int CVMT = 128;             // m per tile (64 u32 pairs)

__launch_bounds__(256)
__global__ void cov_kernel(const ushort* __restrict__ featt, const ushort* __restrict__ xt,
                           float* __restrict__ cov,
                           float* __restrict__ sf, float* __restrict__ sf2,
                           float* __restrict__ sfx, float* __restrict__ sx,
                           float* __restrict__ sx2)
{
    __shared__ unsigned int tl[32 * 66];
    __shared__ float red[4][1040];
    const int sp = blockIdx.x, g = blockIdx.y, b = blockIdx.z;
    const int tid = threadIdx.x;
    const int wv = tid >> 6, l = tid & 63;
    const int c8 = wv * 8;
    const int m0 = sp * CVSEG;

    f32x16 acc;
#pragma unroll
    for (int i = 0; i < 16; ++i) acc[i] = 0.f;
    float cf[8] = {}, cf2[8] = {}, cfx[8] = {}, cx[8] = {}, cx2[8] = {};

    const int ldaddr = (l & 31) * 66 + ((l >> 5) << 2);

    for (int t0 = 0; t0 < CVSEG; t0 += CVMT) {
        const int lim = (CVSEG - t0 < CVMT) ? (CVSEG - t0) : CVMT;
        const int mloc = 2 * l;
        unsigned int pk[8];
        if (mloc + 1 < lim) {
            const size_t base = ((size_t)b * Mn + m0 + t0 + mloc) * Cn + g * Dn + c8;
            const bf16x8 f0 = *(const bf16x8*)(featt + base);
            const bf16x8 f1 = *(const bf16x8*)(featt + base + Cn);
            const bf16x8 x0 = *(const bf16x8*)(xt + base);
            const bf16x8 x1 = *(const bf16x8*)(xt + base + Cn);
#pragma unroll
            for (int e = 0; e < 8; ++e) {
                const float fa = bf2f((ushort)f0[e]), fb = bf2f((ushort)f1[e]);
                const float xa = bf2f((ushort)x0[e]), xb = bf2f((ushort)x1[e]);
                cf[e]  += fa + fb;
                cf2[e]  = fmaf(fa, fa, fmaf(fb, fb, cf2[e]));
                cfx[e]  = fmaf(fa, xa, fmaf(fb, xb, cfx[e]));
                cx[e]  += xa + xb;
                cx2[e]  = fmaf(xa, xa, fmaf(xb, xb, cx2[e]));
                pk[e] = (unsigned int)(ushort)f0[e] | ((unsigned int)(ushort)f1[e] << 16);
            }
        } else {
#pragma unroll
            for (int e = 0; e < 8; ++e) pk[e] = 0;
        }
        __syncthreads();
#pragma unroll
        for (int e = 0; e < 8; ++e)
            tl[(c8 + e) * 66 + l] = pk[e];
        __syncthreads();
#pragma unroll
        for (int s = 0; s < 2; ++s) {
            const int mpb = wv * 16 + s * 8;
            const uint4 rv = *(const uint4*)&tl[ldaddr + mpb];
            union { uint4 u; bf16x8 h; } cvt;
            cvt.u = rv;
            acc = __builtin_amdgcn_mfma_f32_32x32x16_bf16(cvt.h, cvt.h, acc, 0, 0, 0);
        }
    }

#pragma unroll
    for (int i = 0; i < 16; ++i) red[wv][l * 16 + i] = acc[i];
    __syncthreads();
    float* cvb = cov + (size_t)(b * Gn + g) * (Dn * Dn);
    for (int e2 = tid; e2 < 1024; e2 += 256) {
        const int ll = e2 >> 4, reg = e2 & 15;
        const float v = red[0][e2] + red[1][e2] + red[2][e2] + red[3][e2];
        const int i = (reg & 3) + 8 * (reg >> 2) + 4 * (ll >> 5);
        const int j = ll & 31;
        atomicAdd(&cvb[i * Dn + j], v);
    }

#pragma unroll
    for (int e = 0; e < 8; ++e) {
#pragma unroll
        for (int d = 1; d < 64; d <<= 1) {
            cf[e]  += __shfl_xor(cf[e], d);
            cf2[e] += __shfl_xor(cf2[e], d);
            cfx[e] += __shfl_xor(cfx[e], d);
            cx[e]  += __shfl_xor(cx[e], d);
            cx2[e] += __shfl_xor(cx2[e], d);
        }
    }
    if (l == 0) {
        const int ch = b * Cn + g * Dn + c8;
#pragma unroll
        for (int e = 0; e < 8; ++e) {
            atomicAdd(&sf[ch + e],  cf[e]);
            atomicAdd(&sf2[ch + e], cf2[e]);
            atomicAdd(&sfx[ch + e], cfx[e]);
            atomicAdd(&sx[ch + e],  cx[e]);
            atomicAdd(&sx2[ch + e], cx2[e]);
        }
    }
}

// ---------------------------------------------------------------------------
// Newton-Schulz sqrtm per (b,g) 32x32 + row-mean -> s[b,c]
// ---------------------------------------------------------------------------
__device__ __forceinline__ void mm32(float (*A)[33], float (*Bm)[33],
                                     float (*O)[33], int ei, int ej0)
{
    float a0 = 0.f, a1 = 0.f, a2 = 0.f, a3 = 0.f;
#pragma unroll
    for (int k = 0; k < 32; ++k) {
        const float a = A[ei][k];
        a0 = fmaf(a, Bm[k][ej0 + 0], a0);
        a1 = fmaf(a, Bm[k][ej0 + 1], a1);
        a2 = fmaf(a, Bm[k][ej0 + 2], a2);
        a3 = fmaf(a, Bm[k][ej0 + 3], a3);
    }
    O[ei][ej0 + 0] = a0;
    O[ei][ej0 + 1] = a1;
    O[ei][ej0 + 2] = a2;
    O[ei][ej0 + 3] = a3;
    __syncthreads();
}

__launch_bounds__(256)
__global__ void sqrtm_kernel(const float* __restrict__ cov,
                             const float* __restrict__ sf,
                             float* __restrict__ sout)
{
    __shared__ float b0[32][33], b1[32][33], b2[32][33], b3[32][33];
    __shared__ float sh_tr, sh_scale;
    const int bg = blockIdx.x;
    const int b = bg >> 2, g = bg & 3;
    const int tid = threadIdx.x;
    const int ei = (tid * 4) >> 5, ej0 = (tid * 4) & 31;
    const float* cp = cov + (size_t)bg * (Dn * Dn);
    const float* fs = sf + b * Cn + g * Dn;
    const float invM = 1.f / Mn;
    const float mi = fs[ei] * invM;
#pragma unroll
    for (int q = 0; q < 4; ++q)
        b0[ei][ej0 + q] = cp[ei * Dn + ej0 + q] * invM - mi * (fs[ej0 + q] * invM);
    __syncthreads();
    if (tid < 32) {
        float d = b0[tid][tid];
#pragma unroll
        for (int dd = 1; dd < 32; dd <<= 1) d += __shfl_xor(d, dd);
        if (tid == 0) { sh_tr = d; sh_scale = 0.5f * sqrtf(d); }
    }
    __syncthreads();
    const float invtr = 1.f / sh_tr;
#pragma unroll
    for (int q = 0; q < 4; ++q) {
        const float an = b0[ei][ej0 + q] * invtr;
        b0[ei][ej0 + q] = an;
        b1[ei][ej0 + q] = ((ei == ej0 + q) ? 1.5f : 0.f) - 0.5f * an;
    }
    __syncthreads();
    mm32(b0, b1, b2, ei, ej0);  // Y = An @ ZY
    float (*pY)[33] = b2;
    float (*pZ)[33] = b1;
    float (*pF1)[33] = b0;
    float (*pF2)[33] = b3;
#pragma unroll 1
    for (int it = 0; it < 3; ++it) {
        mm32(pZ, pY, pF1, ei, ej0);
#pragma unroll
        for (int q = 0; q < 4; ++q)
            pF1[ei][ej0 + q] = ((ei == ej0 + q) ? 1.5f : 0.f) - 0.5f * pF1[ei][ej0 + q];
        __syncthreads();
        mm32(pY, pF1, pF2, ei, ej0);
        mm32(pF1, pZ, pY, ei, ej0);
        float (*oldZ)[33] = pZ;
        pZ = pY;
        pY = pF2;
        pF2 = oldZ;
    }
    mm32(pZ, pY, pF1, ei, ej0);
#pragma unroll
    for (int q = 0; q < 4; ++q)
        pF1[ei][ej0 + q] = ((ei == ej0 + q) ? 3.f : 0.f) - pF1[ei][ej0 + q];
    __syncthreads();
    mm32(pY, pF1, pF2, ei, ej0);
    if (tid < 32) {
        float t = 0.f;
#pragma unroll
        for (int i = 0; i < 32; ++i) t += pF2[i][tid];
        sout[b * Cn + g * Dn + tid] = t * sh_scale * (1.f / Dn);
    }
}

// ---------------------------------------------------------------------------
// coef1 / coef2 (analytic affine propagation)
// ---------------------------------------------------------------------------
__launch_bounds__(1024)
__global__ void coef1_kernel(const float* __restrict__ sf, const float* __restrict__ sf2,
                             const float* __restrict__ sfx, const float* __restrict__ sx,
                             const float* __restrict__ sx2, const float* __restrict__ s,
                             const float* __restrict__ gng, const float* __restrict__ gnb,
                             const float* __restrict__ bn1g, const float* __restrict__ bn1b,
                             float* __restrict__ Ay, float* __restrict__ By,
                             float* __restrict__ Ah, float* __restrict__ Bh)
{
    __shared__ float smv[Bn * Cn];
    __shared__ float sm2[Bn * Cn];
    __shared__ float smu[Bn * Gn], srs[Bn * Gn];
    __shared__ float sV[Cn];
    const int tid = threadIdx.x;
    const float invM = 1.f / Mn;
    for (int p = tid; p < Bn * Cn; p += 1024) {
        const float sv = s[p];
        smv[p] = fmaf(sv, sf[p], sx[p]) * invM;
        sm2[p] = (sv * sv * sf2[p] + 2.f * sv * sfx[p] + sx2[p]) * invM;
    }
    __syncthreads();
    if (tid < Bn * Gn) {
        const int base = tid * Dn;
        float mu = 0.f, e2 = 0.f;
        for (int c = 0; c < Dn; ++c) { mu += smv[base + c]; e2 += sm2[base + c]; }
        mu *= (1.f / Dn); e2 *= (1.f / Dn);
        smu[tid] = mu;
        srs[tid] = rsqrtf(e2 - mu * mu + GN_EPS);
    }
    __syncthreads();
    for (int p = tid; p < Bn * Cn; p += 1024) {
        const int c = p & (Cn - 1);
        const int bg = p >> 5;
        const float ay = srs[bg] * gng[c];
        const float mv = smv[p];
        sm2[p] = ay * ay * (sm2[p] - mv * mv);
    }
    __syncthreads();
    if (tid < Cn) {
        float V = 0.f;
        for (int b = 0; b < Bn; ++b) {
            const float vy = sm2[b * Cn + tid];
            V += vy / (vy + IN_EPS);
        }
        sV[tid] = V * (1.f / Bn);
    }
    __syncthreads();
    for (int p = tid; p < Bn * Cn; p += 1024) {
        const int c = p & (Cn - 1);
        const int bg = p >> 5;
        const float ay = srs[bg] * gng[c];
        const float mv = smv[p];
        const float by = gnb[c] - smu[bg] * ay;
        const float rsin = rsqrtf(sm2[p] + IN_EPS);
        const float ah = ay * rsin * rsqrtf(sV[c] + BN_EPS) * bn1g[c];
        const float bh = bn1b[c] - ah * mv;
        Ay[p] = ay; By[p] = by; Ah[p] = ah; Bh[p] = bh;
    }
}

__launch_bounds__(1024)
__global__ void coef2_kernel(const float* __restrict__ sum1, const float* __restrict__ sum2,
                             const float* __restrict__ bn2g, const float* __restrict__ bn2b,
                             float* __restrict__ A2, float* __restrict__ B2)
{
    __shared__ float svar[Bn * Cn];
    __shared__ float sV[Cn];
    const int tid = threadIdx.x;
    const float invM = 1.f / Mn;
    for (int p = tid; p < Bn * Cn; p += 1024) {
        const float mu = sum1[p] * invM;
        svar[p] = sum2[p] * invM - mu * mu;
    }
    __syncthreads();
    if (tid < Cn) {
        float V = 0.f;
        for (int b = 0; b < Bn; ++b) {
            const float v = svar[b * Cn + tid];
            V += v / (v + IN_EPS);
        }
        sV[tid] = V * (1.f / Bn);
    }
    __syncthreads();
    for (int p = tid; p < Bn * Cn; p += 1024) {
        const int c = p & (Cn - 1);
        const float mu = sum1[p] * invM;
        const float a2 = rsqrtf(svar[p] + IN_EPS) * rsqrtf(sV[c] + BN_EPS) * bn2g[c];
        A2[p] = a2;
        B2[p] = bn2b[c] - a2 * mu;
    }
}

// ---------------------------------------------------------------------------
extern "C" void kernel_launch(void* const* d_in, const int* in_sizes, int n_in,
                              void* d_out, int out_size, void* d_ws, size_t ws_size,
                              hipStream_t stream)
{
    const float* x      = (const float*)d_in[0];
    const float* w_lin  = (const float*)d_in[1];
    const float* gn_g   = (const float*)d_in[2];
    const float* gn_b   = (const float*)d_in[3];
    const float* bn1g   = (const float*)d_in[4];
    const float* bn1b   = (const float*)d_in[5];
    const float* conv1w = (const float*)d_in[6];
    const float* conv1b = (const float*)d_in[7];
    const float* bn2g   = (const float*)d_in[8];
    const float* bn2b   = (const float*)d_in[9];
    const float* conv2w = (const float*)d_in[10];
    const float* conv2b = (const float*)d_in[11];
    float* out = (float*)d_out;

    const size_t TS = (size_t)Bn * Mn * Cn;
    ushort* xt    = (ushort*)d_ws;
    ushort* featt = xt + TS;
    ushort* h2t   = featt + TS;
    ushort* ybuf  = h2t + TS;
    ushort* wb1   = ybuf + TS;
    ushort* wb2   = wb1 + Cn * Cn;
    ushort* wb3   = wb2 + Cn * Cn;
    float*  fbase = (float*)(wb3 + Cn * Cn);
    float* sarr = fbase;
    float* Ay   = sarr + Bn * Cn;
    float* By   = Ay + Bn * Cn;
    float* Ah   = By + Bn * Cn;
    float* Bh   = Ah + Bn * Cn;
    float* A2   = Bh + Bn * Cn;
    float* B2   = A2 + Bn * Cn;
    float* zbase = B2 + Bn * Cn;
    float* cov  = zbase;
    float* sf   = cov + Bn * Gn * Dn * Dn;
    float* sf2  = sf + Bn * Cn;
    float* sfx  = sf2 + Bn * Cn;
    float* sx   = sfx + Bn * Cn;
    float* sx2  = sx + Bn * Cn;
    float* sum1 = sx2 + Bn * Cn;
    float* sum2 = sum1 + Bn * Cn;
    const size_t zfloats = (size_t)Bn * Gn * Dn * Dn + 7 * Bn * Cn;

    hipMemsetAsync(zbase, 0, zfloats * sizeof(float), stream);

    prep_w3<<<dim3(192), 256, 0, stream>>>(w_lin, conv1w, conv2w, wb1);
    prep_xt<<<dim3(Mn / 32, Cn / 32, Bn), 256, 0, stream>>>(x, xt);

    const dim3 ggrid((Mn + 127) / 128, Bn);

    // 1) featt = xt @ W1^T   ([b][m][o] bf16)
    mgemm_kernel<0><<<ggrid, 256, 0, stream>>>(
        wb1, xt, nullptr, featt, nullptr, nullptr, nullptr, nullptr, nullptr,
        nullptr, nullptr, nullptr, nullptr, nullptr);

    // 2) covariance (MFMA) + channel sums
    cov_kernel<<<dim3(CVSPLIT, Gn, Bn), 256, 0, stream>>>(featt, xt, cov, sf, sf2, sfx, sx, sx2);

    // 3) Newton-Schulz sqrtm -> s
    sqrtm_kernel<<<Bn * Gn, 256, 0, stream>>>(cov, sf, sarr);

    // 4) affine coefficients (GN + first IN/BN/ReLU)
    coef1_kernel<<<1, 1024, 0, stream>>>(sf, sf2, sfx, sx, sx2, sarr,
                                         gn_g, gn_b, bn1g, bn1b, Ay, By, Ah, Bh);

    // 5) h2t = relu(Ah*(s*featt+xt)+Bh) @ W2^T + b1, writes ybuf, stats
    mgemm_kernel<1><<<ggrid, 256, 0, stream>>>(
        wb2, featt, xt, h2t, nullptr, conv1b, sarr, Ah, Bh,
        Ay, By, ybuf, sum1, sum2);

    // 6) second-stage affine coefficients
    coef2_kernel<<<1, 1024, 0, stream>>>(sum1, sum2, bn2g, bn2b, A2, B2);

    // 7) out = relu(A2*h2t+B2) @ W3^T + b2 + y   ([b][o][m] fp32)
    mgemm_kernel<2><<<ggrid, 256, 0, stream>>>(
        wb3, h2t, nullptr, nullptr, out, conv2b, nullptr, A2, B2,
        nullptr, nullptr, ybuf, nullptr, nullptr);
}

// Round 8
// 165.386 us; speedup vs baseline: 1.6313x; 1.0461x over previous
//
#include <hip/hip_runtime.h>

constexpr int Bn = 32;
constexpr int Cn = 128;
constexpr int Mn = 4000;
constexpr int Gn = 4;
constexpr int Dn = 32;   // C / G
constexpr float GN_EPS = 1e-5f;
constexpr float IN_EPS = 1e-3f;
constexpr float BN_EPS = 1e-5f;

typedef __attribute__((ext_vector_type(8))) short bf16x8;
typedef __attribute__((ext_vector_type(4))) float f32x4;
typedef __attribute__((ext_vector_type(16))) float f32x16;

__device__ __forceinline__ float bf2f(ushort u) {
    union { unsigned int u; float f; } v;
    v.u = ((unsigned int)u) << 16;
    return v.f;
}
__device__ __forceinline__ ushort f2bf(float f) {
    union { float f; unsigned int u; } v;
    v.f = f;
    unsigned int r = v.u + 0x7FFFu + ((v.u >> 16) & 1u);
    return (ushort)(r >> 16);
}

// ---------------------------------------------------------------------------
// prep_w3: three fp32 W[128][128] -> bf16, one launch
// ---------------------------------------------------------------------------
__global__ void prep_w3(const float* __restrict__ w0, const float* __restrict__ w1,
                        const float* __restrict__ w2, ushort* __restrict__ wb) {
    const int i = blockIdx.x * 256 + threadIdx.x;   // 49152 total
    const int which = i >> 14;
    const int off = i & 16383;
    const float v = (which == 0) ? w0[off] : (which == 1) ? w1[off] : w2[off];
    wb[i] = f2bf(v);
}

// ---------------------------------------------------------------------------
// prep_xt: x [b][c][m] fp32 -> xt [b][m][c] bf16
// ---------------------------------------------------------------------------
__launch_bounds__(256)
__global__ void prep_xt(const float* __restrict__ x, ushort* __restrict__ xt) {
    __shared__ float tl[32 * 33];
    const int mb = blockIdx.x * 32, cb = blockIdx.y * 32, b = blockIdx.z;
    const int tid = threadIdx.x;
    const int mi = tid & 31;
#pragma unroll
    for (int p = 0; p < 4; ++p) {
        const int ci = (tid >> 5) + 8 * p;
        tl[ci * 33 + mi] = x[((size_t)b * Cn + cb + ci) * Mn + mb + mi];
    }
    __syncthreads();
#pragma unroll
    for (int p = 0; p < 4; ++p) {
        const int mi2 = (tid >> 5) + 8 * p;
        const int ci2 = tid & 31;
        xt[((size_t)b * Mn + mb + mi2) * Cn + cb + ci2] = f2bf(tl[ci2 * 33 + mi2]);
    }
}

// ---------------------------------------------------------------------------
// MFMA GEMM: D[b][m][o] = sum_c T(src[b][m][c]) * W[o][c]
// block 256 thr = 4 waves, tile 128m x 128o, W+coefs in LDS, ALL a-frag
// loads for both half-tiles hoisted (16 in flight, single wait).
// A-rows are clamped (not masked): garbage rows only affect their own
// output row (16x16x32 MFMA is row-wise), which is never stored.
// grid ((Mn+127)/128, Bn)
// ---------------------------------------------------------------------------
constexpr int WPAD = 136;

template <int MODE>
__launch_bounds__(256, 3)
__global__ void mgemm_kernel(const ushort* __restrict__ Wb,
                             const ushort* __restrict__ src,
                             const ushort* __restrict__ xsrc,
                             ushort* __restrict__ dst_bf,
                             float* __restrict__ dst_f32,
                             const float* __restrict__ bias,
                             const float* __restrict__ sarr,
                             const float* __restrict__ tA,
                             const float* __restrict__ tB,
                             const float* __restrict__ Ayc,
                             const float* __restrict__ Byc,
                             ushort* __restrict__ ybuf,
                             float* __restrict__ sum1,
                             float* __restrict__ sum2)
{
    __shared__ ushort Wl[128 * WPAD];     // 34816 B; reused by epilogues
    __shared__ float coefLDS[640];        // tA,tB,s,Ay,By  ([arr*128 + c])
    const int b = blockIdx.y;
    const int mb = blockIdx.x * 128;
    const int tid = threadIdx.x;
    const int wv = tid >> 6, l = tid & 63;
    const int li = l & 15, lg = l >> 4;

    // stage W -> LDS
#pragma unroll
    for (int p = 0; p < 8; ++p) {
        const int u = tid + 256 * p;
        const int o = u >> 4, c8 = (u & 15) * 8;
        *(bf16x8*)&Wl[o * WPAD + c8] = *(const bf16x8*)(Wb + o * 128 + c8);
    }
    // stage coefs -> LDS
    if (MODE >= 1) {
        const int ncoef = (MODE == 1) ? 640 : 256;
        for (int idx = tid; idx < ncoef; idx += 256) {
            const int arr = idx >> 7, c = idx & 127;
            float v;
            switch (arr) {
                case 0: v = tA[b * Cn + c]; break;
                case 1: v = tB[b * Cn + c]; break;
                case 2: v = sarr[b * Cn + c]; break;
                case 3: v = Ayc[b * Cn + c]; break;
                default: v = Byc[b * Cn + c]; break;
            }
            coefLDS[idx] = v;
        }
    }
    __syncthreads();

    f32x4 acc[2][8];
#pragma unroll
    for (int t = 0; t < 2; ++t)
#pragma unroll
        for (int j = 0; j < 8; ++j)
#pragma unroll
            for (int r = 0; r < 4; ++r) acc[t][j][r] = 0.f;

    // phase 1: issue ALL raw loads for both half-tiles (clamped rows)
    bf16x8 fr[2][4], xr[2][4];
    bool mokv[2];
    size_t qrowv[2];
#pragma unroll
    for (int t = 0; t < 2; ++t) {
        const int ma = mb + wv * 32 + t * 16 + li;
        mokv[t] = ma < Mn;
        const int mc = mokv[t] ? ma : (Mn - 1);
        qrowv[t] = ((size_t)b * Mn + mc) * Cn;
#pragma unroll
        for (int kb = 0; kb < 4; ++kb) {
            const int cl = kb * 32 + 8 * lg;
            fr[t][kb] = *(const bf16x8*)(src + qrowv[t] + cl);
            if (MODE == 1)
                xr[t][kb] = *(const bf16x8*)(xsrc + qrowv[t] + cl);
        }
    }

    // phase 2: transform + MFMA
#pragma unroll
    for (int t = 0; t < 2; ++t) {
#pragma unroll
        for (int kb = 0; kb < 4; ++kb) {
            const int cl = kb * 32 + 8 * lg;
            bf16x8 af;
            if (MODE == 0) {
                af = fr[t][kb];
            } else if (MODE == 1) {
                const float4 a0 = *(const float4*)&coefLDS[0 + cl];
                const float4 a1 = *(const float4*)&coefLDS[0 + cl + 4];
                const float4 b0 = *(const float4*)&coefLDS[128 + cl];
                const float4 b1 = *(const float4*)&coefLDS[128 + cl + 4];
                const float4 s0 = *(const float4*)&coefLDS[256 + cl];
                const float4 s1 = *(const float4*)&coefLDS[256 + cl + 4];
                const float4 y0 = *(const float4*)&coefLDS[384 + cl];
                const float4 y1 = *(const float4*)&coefLDS[384 + cl + 4];
                const float4 z0 = *(const float4*)&coefLDS[512 + cl];
                const float4 z1 = *(const float4*)&coefLDS[512 + cl + 4];
                const float tAv[8] = {a0.x,a0.y,a0.z,a0.w,a1.x,a1.y,a1.z,a1.w};
                const float tBv[8] = {b0.x,b0.y,b0.z,b0.w,b1.x,b1.y,b1.z,b1.w};
                const float svv[8] = {s0.x,s0.y,s0.z,s0.w,s1.x,s1.y,s1.z,s1.w};
                const float ayv[8] = {y0.x,y0.y,y0.z,y0.w,y1.x,y1.y,y1.z,y1.w};
                const float byv[8] = {z0.x,z0.y,z0.z,z0.w,z1.x,z1.y,z1.z,z1.w};
                bf16x8 y8;
#pragma unroll
                for (int e = 0; e < 8; ++e) {
                    const float vv = fmaf(svv[e], bf2f((ushort)fr[t][kb][e]), bf2f((ushort)xr[t][kb][e]));
                    af[e] = (short)f2bf(fmaxf(fmaf(tAv[e], vv, tBv[e]), 0.f));
                    y8[e] = (short)f2bf(fmaf(ayv[e], vv, byv[e]));
                }
                if (mokv[t]) *(bf16x8*)(ybuf + qrowv[t] + cl) = y8;
            } else {
                const float4 a0 = *(const float4*)&coefLDS[0 + cl];
                const float4 a1 = *(const float4*)&coefLDS[0 + cl + 4];
                const float4 b0 = *(const float4*)&coefLDS[128 + cl];
                const float4 b1 = *(const float4*)&coefLDS[128 + cl + 4];
                const float tAv[8] = {a0.x,a0.y,a0.z,a0.w,a1.x,a1.y,a1.z,a1.w};
                const float tBv[8] = {b0.x,b0.y,b0.z,b0.w,b1.x,b1.y,b1.z,b1.w};
#pragma unroll
                for (int e = 0; e < 8; ++e)
                    af[e] = (short)f2bf(fmaxf(fmaf(tAv[e], bf2f((ushort)fr[t][kb][e]), tBv[e]), 0.f));
            }
#pragma unroll
            for (int j = 0; j < 8; ++j) {
                const bf16x8 bj = *(const bf16x8*)&Wl[(j * 16 + li) * WPAD + cl];
                acc[t][j] = __builtin_amdgcn_mfma_f32_16x16x32_bf16(af, bj, acc[t][j], 0, 0, 0);
            }
        }
    }

    // ---------------- epilogues ----------------
    if constexpr (MODE <= 1) {
        // stage (+bias) as bf16 into Wl[m][o], then coalesced bf16x8 stores
        __syncthreads();
#pragma unroll
        for (int t = 0; t < 2; ++t)
#pragma unroll
            for (int j = 0; j < 8; ++j) {
                const int o = j * 16 + li;
                const float bv = (MODE == 1) ? bias[o] : 0.f;
#pragma unroll
                for (int r = 0; r < 4; ++r) {
                    const int ml = wv * 32 + t * 16 + lg * 4 + r;
                    Wl[ml * WPAD + o] = f2bf(acc[t][j][r] + bv);
                }
            }
        __syncthreads();
        const int c8 = (tid & 15) * 8;
        float s1a[8] = {}, s2a[8] = {};
#pragma unroll
        for (int p = 0; p < 8; ++p) {
            const int row = (tid >> 4) + 16 * p;
            const int m = mb + row;
            const bf16x8 v8 = *(const bf16x8*)&Wl[row * WPAD + c8];
            if (m < Mn) {
                *(bf16x8*)(dst_bf + ((size_t)b * Mn + m) * Cn + c8) = v8;
                if (MODE == 1) {
#pragma unroll
                    for (int e = 0; e < 8; ++e) {
                        const float f = bf2f((ushort)v8[e]);
                        s1a[e] += f;
                        s2a[e] = fmaf(f, f, s2a[e]);
                    }
                }
            }
        }
        if (MODE == 1) {
#pragma unroll
            for (int e = 0; e < 8; ++e) {
                s1a[e] += __shfl_xor(s1a[e], 16); s1a[e] += __shfl_xor(s1a[e], 32);
                s2a[e] += __shfl_xor(s2a[e], 16); s2a[e] += __shfl_xor(s2a[e], 32);
            }
            __syncthreads();
            float* red = (float*)&Wl[0];   // [wv][oc 0..15][16]
            if (l < 16) {
#pragma unroll
                for (int e = 0; e < 8; ++e) {
                    red[(wv * 16 + l) * 16 + e] = s1a[e];
                    red[(wv * 16 + l) * 16 + 8 + e] = s2a[e];
                }
            }
            __syncthreads();
            if (tid < 128) {
                const int oc = tid >> 3, e = tid & 7;
                const int o = oc * 8 + e;
                const float t1 = red[(0 + oc) * 16 + e] + red[(16 + oc) * 16 + e] +
                                 red[(32 + oc) * 16 + e] + red[(48 + oc) * 16 + e];
                const float t2 = red[(0 + oc) * 16 + 8 + e] + red[(16 + oc) * 16 + 8 + e] +
                                 red[(32 + oc) * 16 + 8 + e] + red[(48 + oc) * 16 + 8 + e];
                atomicAdd(&sum1[b * Cn + o], t1);
                atomicAdd(&sum2[b * Cn + o], t2);
            }
        }
    } else {
        // MODE 2: stage y tile into Wl (coalesced), fold bias+y, transpose, store
        float* TR = (float*)&Wl[0];   // 64*132*4 = 33792 B <= 34816
        __syncthreads();
#pragma unroll
        for (int p = 0; p < 8; ++p) {
            const int u = tid + 256 * p;
            const int row = u >> 4, c8 = (u & 15) * 8;
            bf16x8 yv;
#pragma unroll
            for (int e = 0; e < 8; ++e) yv[e] = 0;
            if (mb + row < Mn)
                yv = *(const bf16x8*)(ybuf + ((size_t)b * Mn + mb + row) * Cn + c8);
            *(bf16x8*)&Wl[row * WPAD + c8] = yv;
        }
        __syncthreads();
#pragma unroll
        for (int j = 0; j < 8; ++j) {
            const int o = j * 16 + li;
            const float bv = bias[o];
#pragma unroll
            for (int t = 0; t < 2; ++t)
#pragma unroll
                for (int r = 0; r < 4; ++r) {
                    const int ml = wv * 32 + t * 16 + lg * 4 + r;
                    acc[t][j][r] += bv + bf2f(Wl[ml * WPAD + o]);
                }
        }
#pragma unroll
        for (int h = 0; h < 2; ++h) {
            __syncthreads();
#pragma unroll
            for (int jj = 0; jj < 4; ++jj) {
                const int j = h * 4 + jj;
#pragma unroll
                for (int t = 0; t < 2; ++t)
#pragma unroll
                    for (int r = 0; r < 4; ++r) {
                        const int ml = wv * 32 + t * 16 + lg * 4 + r;
                        TR[(jj * 16 + li) * 132 + ml] = acc[t][j][r];
                    }
            }
            __syncthreads();
#pragma unroll
            for (int p = 0; p < 8; ++p) {
                const int ol = tid >> 2;                 // 0..63
                const int q = (tid & 3) + 4 * p;         // 0..31
                const int m = mb + 4 * q;
                if (m < Mn) {
                    const f32x4 v = *(const f32x4*)&TR[ol * 132 + 4 * q];
                    *(f32x4*)(dst_f32 + ((size_t)b * Cn + h * 64 + ol) * Mn + m) = v;
                }
            }
        }
    }
}

// ---------------------------------------------------------------------------
// Covariance via MFMA (A==B fragment trick) + channel sums.
// grid: (CVSPLIT, Gn, Bn), 256 threads = 4 waves.
// ---------------------------------------------------------------------------
constexpr int CVSPLIT = 8;
constexpr int CVSEG = Mn / CVSPLIT;   // 500
constexpr int CVMT = 128;             // m per tile (64 u32 pairs)

__launch_bounds__(256)
__global__ void cov_kernel(const ushort* __restrict__ featt, const ushort* __restrict__ xt,
                           float* __restrict__ cov,
                           float* __restrict__ sf, float* __restrict__ sf2,
                           float* __restrict__ sfx, float* __restrict__ sx,
                           float* __restrict__ sx2)
{
    __shared__ unsigned int tl[32 * 66];
    __shared__ float red[4][1040];
    const int sp = blockIdx.x, g = blockIdx.y, b = blockIdx.z;
    const int tid = threadIdx.x;
    const int wv = tid >> 6, l = tid & 63;
    const int c8 = wv * 8;
    const int m0 = sp * CVSEG;

    f32x16 acc;
#pragma unroll
    for (int i = 0; i < 16; ++i) acc[i] = 0.f;
    float cf[8] = {}, cf2[8] = {}, cfx[8] = {}, cx[8] = {}, cx2[8] = {};

    const int ldaddr = (l & 31) * 66 + ((l >> 5) << 2);

    for (int t0 = 0; t0 < CVSEG; t0 += CVMT) {
        const int lim = (CVSEG - t0 < CVMT) ? (CVSEG - t0) : CVMT;
        const int mloc = 2 * l;
        unsigned int pk[8];
        if (mloc + 1 < lim) {
            const size_t base = ((size_t)b * Mn + m0 + t0 + mloc) * Cn + g * Dn + c8;
            const bf16x8 f0 = *(const bf16x8*)(featt + base);
            const bf16x8 f1 = *(const bf16x8*)(featt + base + Cn);
            const bf16x8 x0 = *(const bf16x8*)(xt + base);
            const bf16x8 x1 = *(const bf16x8*)(xt + base + Cn);
#pragma unroll
            for (int e = 0; e < 8; ++e) {
                const float fa = bf2f((ushort)f0[e]), fb = bf2f((ushort)f1[e]);
                const float xa = bf2f((ushort)x0[e]), xb = bf2f((ushort)x1[e]);
                cf[e]  += fa + fb;
                cf2[e]  = fmaf(fa, fa, fmaf(fb, fb, cf2[e]));
                cfx[e]  = fmaf(fa, xa, fmaf(fb, xb, cfx[e]));
                cx[e]  += xa + xb;
                cx2[e]  = fmaf(xa, xa, fmaf(xb, xb, cx2[e]));
                pk[e] = (unsigned int)(ushort)f0[e] | ((unsigned int)(ushort)f1[e] << 16);
            }
        } else {
#pragma unroll
            for (int e = 0; e < 8; ++e) pk[e] = 0;
        }
        __syncthreads();
#pragma unroll
        for (int e = 0; e < 8; ++e)
            tl[(c8 + e) * 66 + l] = pk[e];
        __syncthreads();
#pragma unroll
        for (int s = 0; s < 2; ++s) {
            const int mpb = wv * 16 + s * 8;
            const uint4 rv = *(const uint4*)&tl[ldaddr + mpb];
            union { uint4 u; bf16x8 h; } cvt;
            cvt.u = rv;
            acc = __builtin_amdgcn_mfma_f32_32x32x16_bf16(cvt.h, cvt.h, acc, 0, 0, 0);
        }
    }

#pragma unroll
    for (int i = 0; i < 16; ++i) red[wv][l * 16 + i] = acc[i];
    __syncthreads();
    float* cvb = cov + (size_t)(b * Gn + g) * (Dn * Dn);
    for (int e2 = tid; e2 < 1024; e2 += 256) {
        const int ll = e2 >> 4, reg = e2 & 15;
        const float v = red[0][e2] + red[1][e2] + red[2][e2] + red[3][e2];
        const int i = (reg & 3) + 8 * (reg >> 2) + 4 * (ll >> 5);
        const int j = ll & 31;
        atomicAdd(&cvb[i * Dn + j], v);
    }

#pragma unroll
    for (int e = 0; e < 8; ++e) {
#pragma unroll
        for (int d = 1; d < 64; d <<= 1) {
            cf[e]  += __shfl_xor(cf[e], d);
            cf2[e] += __shfl_xor(cf2[e], d);
            cfx[e] += __shfl_xor(cfx[e], d);
            cx[e]  += __shfl_xor(cx[e], d);
            cx2[e] += __shfl_xor(cx2[e], d);
        }
    }
    if (l == 0) {
        const int ch = b * Cn + g * Dn + c8;
#pragma unroll
        for (int e = 0; e < 8; ++e) {
            atomicAdd(&sf[ch + e],  cf[e]);
            atomicAdd(&sf2[ch + e], cf2[e]);
            atomicAdd(&sfx[ch + e], cfx[e]);
            atomicAdd(&sx[ch + e],  cx[e]);
            atomicAdd(&sx2[ch + e], cx2[e]);
        }
    }
}

// ---------------------------------------------------------------------------
// Newton-Schulz sqrtm per (b,g) 32x32 + row-mean -> s[b,c]
// ---------------------------------------------------------------------------
__device__ __forceinline__ void mm32(float (*A)[33], float (*Bm)[33],
                                     float (*O)[33], int ei, int ej0)
{
    float a0 = 0.f, a1 = 0.f, a2 = 0.f, a3 = 0.f;
#pragma unroll
    for (int k = 0; k < 32; ++k) {
        const float a = A[ei][k];
        a0 = fmaf(a, Bm[k][ej0 + 0], a0);
        a1 = fmaf(a, Bm[k][ej0 + 1], a1);
        a2 = fmaf(a, Bm[k][ej0 + 2], a2);
        a3 = fmaf(a, Bm[k][ej0 + 3], a3);
    }
    O[ei][ej0 + 0] = a0;
    O[ei][ej0 + 1] = a1;
    O[ei][ej0 + 2] = a2;
    O[ei][ej0 + 3] = a3;
    __syncthreads();
}

__launch_bounds__(256)
__global__ void sqrtm_kernel(const float* __restrict__ cov,
                             const float* __restrict__ sf,
                             float* __restrict__ sout)
{
    __shared__ float b0[32][33], b1[32][33], b2[32][33], b3[32][33];
    __shared__ float sh_tr, sh_scale;
    const int bg = blockIdx.x;
    const int b = bg >> 2, g = bg & 3;
    const int tid = threadIdx.x;
    const int ei = (tid * 4) >> 5, ej0 = (tid * 4) & 31;
    const float* cp = cov + (size_t)bg * (Dn * Dn);
    const float* fs = sf + b * Cn + g * Dn;
    const float invM = 1.f / Mn;
    const float mi = fs[ei] * invM;
#pragma unroll
    for (int q = 0; q < 4; ++q)
        b0[ei][ej0 + q] = cp[ei * Dn + ej0 + q] * invM - mi * (fs[ej0 + q] * invM);
    __syncthreads();
    if (tid < 32) {
        float d = b0[tid][tid];
#pragma unroll
        for (int dd = 1; dd < 32; dd <<= 1) d += __shfl_xor(d, dd);
        if (tid == 0) { sh_tr = d; sh_scale = 0.5f * sqrtf(d); }
    }
    __syncthreads();
    const float invtr = 1.f / sh_tr;
#pragma unroll
    for (int q = 0; q < 4; ++q) {
        const float an = b0[ei][ej0 + q] * invtr;
        b0[ei][ej0 + q] = an;
        b1[ei][ej0 + q] = ((ei == ej0 + q) ? 1.5f : 0.f) - 0.5f * an;
    }
    __syncthreads();
    mm32(b0, b1, b2, ei, ej0);  // Y = An @ ZY
    float (*pY)[33] = b2;
    float (*pZ)[33] = b1;
    float (*pF1)[33] = b0;
    float (*pF2)[33] = b3;
#pragma unroll 1
    for (int it = 0; it < 3; ++it) {
        mm32(pZ, pY, pF1, ei, ej0);
#pragma unroll
        for (int q = 0; q < 4; ++q)
            pF1[ei][ej0 + q] = ((ei == ej0 + q) ? 1.5f : 0.f) - 0.5f * pF1[ei][ej0 + q];
        __syncthreads();
        mm32(pY, pF1, pF2, ei, ej0);
        mm32(pF1, pZ, pY, ei, ej0);
        float (*oldZ)[33] = pZ;
        pZ = pY;
        pY = pF2;
        pF2 = oldZ;
    }
    mm32(pZ, pY, pF1, ei, ej0);
#pragma unroll
    for (int q = 0; q < 4; ++q)
        pF1[ei][ej0 + q] = ((ei == ej0 + q) ? 3.f : 0.f) - pF1[ei][ej0 + q];
    __syncthreads();
    mm32(pY, pF1, pF2, ei, ej0);
    if (tid < 32) {
        float t = 0.f;
#pragma unroll
        for (int i = 0; i < 32; ++i) t += pF2[i][tid];
        sout[b * Cn + g * Dn + tid] = t * sh_scale * (1.f / Dn);
    }
}

// ---------------------------------------------------------------------------
// coef1 / coef2 (analytic affine propagation)
// ---------------------------------------------------------------------------
__launch_bounds__(1024)
__global__ void coef1_kernel(const float* __restrict__ sf, const float* __restrict__ sf2,
                             const float* __restrict__ sfx, const float* __restrict__ sx,
                             const float* __restrict__ sx2, const float* __restrict__ s,
                             const float* __restrict__ gng, const float* __restrict__ gnb,
                             const float* __restrict__ bn1g, const float* __restrict__ bn1b,
                             float* __restrict__ Ay, float* __restrict__ By,
                             float* __restrict__ Ah, float* __restrict__ Bh)
{
    __shared__ float smv[Bn * Cn];
    __shared__ float sm2[Bn * Cn];
    __shared__ float smu[Bn * Gn], srs[Bn * Gn];
    __shared__ float sV[Cn];
    const int tid = threadIdx.x;
    const float invM = 1.f / Mn;
    for (int p = tid; p < Bn * Cn; p += 1024) {
        const float sv = s[p];
        smv[p] = fmaf(sv, sf[p], sx[p]) * invM;
        sm2[p] = (sv * sv * sf2[p] + 2.f * sv * sfx[p] + sx2[p]) * invM;
    }
    __syncthreads();
    if (tid < Bn * Gn) {
        const int base = tid * Dn;
        float mu = 0.f, e2 = 0.f;
        for (int c = 0; c < Dn; ++c) { mu += smv[base + c]; e2 += sm2[base + c]; }
        mu *= (1.f / Dn); e2 *= (1.f / Dn);
        smu[tid] = mu;
        srs[tid] = rsqrtf(e2 - mu * mu + GN_EPS);
    }
    __syncthreads();
    for (int p = tid; p < Bn * Cn; p += 1024) {
        const int c = p & (Cn - 1);
        const int bg = p >> 5;
        const float ay = srs[bg] * gng[c];
        const float mv = smv[p];
        sm2[p] = ay * ay * (sm2[p] - mv * mv);
    }
    __syncthreads();
    if (tid < Cn) {
        float V = 0.f;
        for (int b = 0; b < Bn; ++b) {
            const float vy = sm2[b * Cn + tid];
            V += vy / (vy + IN_EPS);
        }
        sV[tid] = V * (1.f / Bn);
    }
    __syncthreads();
    for (int p = tid; p < Bn * Cn; p += 1024) {
        const int c = p & (Cn - 1);
        const int bg = p >> 5;
        const float ay = srs[bg] * gng[c];
        const float mv = smv[p];
        const float by = gnb[c] - smu[bg] * ay;
        const float rsin = rsqrtf(sm2[p] + IN_EPS);
        const float ah = ay * rsin * rsqrtf(sV[c] + BN_EPS) * bn1g[c];
        const float bh = bn1b[c] - ah * mv;
        Ay[p] = ay; By[p] = by; Ah[p] = ah; Bh[p] = bh;
    }
}

__launch_bounds__(1024)
__global__ void coef2_kernel(const float* __restrict__ sum1, const float* __restrict__ sum2,
                             const float* __restrict__ bn2g, const float* __restrict__ bn2b,
                             float* __restrict__ A2, float* __restrict__ B2)
{
    __shared__ float svar[Bn * Cn];
    __shared__ float sV[Cn];
    const int tid = threadIdx.x;
    const float invM = 1.f / Mn;
    for (int p = tid; p < Bn * Cn; p += 1024) {
        const float mu = sum1[p] * invM;
        svar[p] = sum2[p] * invM - mu * mu;
    }
    __syncthreads();
    if (tid < Cn) {
        float V = 0.f;
        for (int b = 0; b < Bn; ++b) {
            const float v = svar[b * Cn + tid];
            V += v / (v + IN_EPS);
        }
        sV[tid] = V * (1.f / Bn);
    }
    __syncthreads();
    for (int p = tid; p < Bn * Cn; p += 1024) {
        const int c = p & (Cn - 1);
        const float mu = sum1[p] * invM;
        const float a2 = rsqrtf(svar[p] + IN_EPS) * rsqrtf(sV[c] + BN_EPS) * bn2g[c];
        A2[p] = a2;
        B2[p] = bn2b[c] - a2 * mu;
    }
}

// ---------------------------------------------------------------------------
extern "C" void kernel_launch(void* const* d_in, const int* in_sizes, int n_in,
                              void* d_out, int out_size, void* d_ws, size_t ws_size,
                              hipStream_t stream)
{
    const float* x      = (const float*)d_in[0];
    const float* w_lin  = (const float*)d_in[1];
    const float* gn_g   = (const float*)d_in[2];
    const float* gn_b   = (const float*)d_in[3];
    const float* bn1g   = (const float*)d_in[4];
    const float* bn1b   = (const float*)d_in[5];
    const float* conv1w = (const float*)d_in[6];
    const float* conv1b = (const float*)d_in[7];
    const float* bn2g   = (const float*)d_in[8];
    const float* bn2b   = (const float*)d_in[9];
    const float* conv2w = (const float*)d_in[10];
    const float* conv2b = (const float*)d_in[11];
    float* out = (float*)d_out;

    const size_t TS = (size_t)Bn * Mn * Cn;
    ushort* xt    = (ushort*)d_ws;
    ushort* featt = xt + TS;
    ushort* h2t   = featt + TS;
    ushort* ybuf  = h2t + TS;
    ushort* wb1   = ybuf + TS;
    ushort* wb2   = wb1 + Cn * Cn;
    ushort* wb3   = wb2 + Cn * Cn;
    float*  fbase = (float*)(wb3 + Cn * Cn);
    float* sarr = fbase;
    float* Ay   = sarr + Bn * Cn;
    float* By   = Ay + Bn * Cn;
    float* Ah   = By + Bn * Cn;
    float* Bh   = Ah + Bn * Cn;
    float* A2   = Bh + Bn * Cn;
    float* B2   = A2 + Bn * Cn;
    float* zbase = B2 + Bn * Cn;
    float* cov  = zbase;
    float* sf   = cov + Bn * Gn * Dn * Dn;
    float* sf2  = sf + Bn * Cn;
    float* sfx  = sf2 + Bn * Cn;
    float* sx   = sfx + Bn * Cn;
    float* sx2  = sx + Bn * Cn;
    float* sum1 = sx2 + Bn * Cn;
    float* sum2 = sum1 + Bn * Cn;
    const size_t zfloats = (size_t)Bn * Gn * Dn * Dn + 7 * Bn * Cn;

    hipMemsetAsync(zbase, 0, zfloats * sizeof(float), stream);

    prep_w3<<<dim3(192), 256, 0, stream>>>(w_lin, conv1w, conv2w, wb1);
    prep_xt<<<dim3(Mn / 32, Cn / 32, Bn), 256, 0, stream>>>(x, xt);

    const dim3 ggrid((Mn + 127) / 128, Bn);

    // 1) featt = xt @ W1^T   ([b][m][o] bf16)
    mgemm_kernel<0><<<ggrid, 256, 0, stream>>>(
        wb1, xt, nullptr, featt, nullptr, nullptr, nullptr, nullptr, nullptr,
        nullptr, nullptr, nullptr, nullptr, nullptr);

    // 2) covariance (MFMA) + channel sums
    cov_kernel<<<dim3(CVSPLIT, Gn, Bn), 256, 0, stream>>>(featt, xt, cov, sf, sf2, sfx, sx, sx2);

    // 3) Newton-Schulz sqrtm -> s
    sqrtm_kernel<<<Bn * Gn, 256, 0, stream>>>(cov, sf, sarr);

    // 4) affine coefficients (GN + first IN/BN/ReLU)
    coef1_kernel<<<1, 1024, 0, stream>>>(sf, sf2, sfx, sx, sx2, sarr,
                                         gn_g, gn_b, bn1g, bn1b, Ay, By, Ah, Bh);

    // 5) h2t = relu(Ah*(s*featt+xt)+Bh) @ W2^T + b1, writes ybuf, stats
    mgemm_kernel<1><<<ggrid, 256, 0, stream>>>(
        wb2, featt, xt, h2t, nullptr, conv1b, sarr, Ah, Bh,
        Ay, By, ybuf, sum1, sum2);

    // 6) second-stage affine coefficients
    coef2_kernel<<<1, 1024, 0, stream>>>(sum1, sum2, bn2g, bn2b, A2, B2);

    // 7) out = relu(A2*h2t+B2) @ W3^T + b2 + y   ([b][o][m] fp32)
    mgemm_kernel<2><<<ggrid, 256, 0, stream>>>(
        wb3, h2t, nullptr, nullptr, out, conv2b, nullptr, A2, B2,
        nullptr, nullptr, ybuf, nullptr, nullptr);
}